// Round 3
// baseline (7466.546 us; speedup 1.0000x reference)
//
#include <hip/hip_runtime.h>

// PointNet++ front-end: FPS (B=4, N=16384, NPOINT=1024) + ball query nsample=1.
// xyz layout [B,3,N]. Output int32 [B,NPOINT,1].
//
// Round-3 design: FPS split across G=8 blocks per batch (32 CUs), synced per
// iteration with device-scope atomics through the LLC (flag = packed argmax
// key). All blocks co-resident (32 << 256 CUs) so the spin sync cannot hang.

constexpr int   N_PTS  = 16384;
constexpr int   NPOINT = 1024;
constexpr float BIGF   = 1e10f;

// ---- multi-block FPS config ----
constexpr int T     = 512;          // threads per block (8 waves)
constexpr int G     = 8;            // blocks per batch
constexpr int CHUNK = N_PTS / G;    // 2048 points per block
constexpr int KPT   = CHUNK / T;    // 4 points per thread (registers, no AGPR)
constexpr int NWAVE = T / 64;       // 8

// Packed argmax key: dists (and x-coords) are >= 0 so IEEE bits are monotone.
// High 32 = value bits, low 16 = (N-1-idx): u64 max == (max val, tie -> min
// idx) == np.argmax first-occurrence semantics, globally across blocks.
__device__ inline unsigned long long pack_key(float v, int idx) {
    return ((unsigned long long)__float_as_uint(v) << 32) |
           (unsigned)(N_PTS - 1 - idx);
}
__device__ inline int key_idx(unsigned long long k) {
    return N_PTS - 1 - (int)(k & 0xFFFFu);
}

// ---------------------------------------------------------------------------
// Multi-block FPS. Per reduction round r: wave butterfly -> LDS (double-
// buffered, one barrier) -> block key -> leader atomicMax into keyArr[b][r],
// release fetch_add on cnt[b][r]; everyone acquire-polls cnt==G then reads
// the global key. Distance formula exactly as numpy: ((dx*dx+dy*dy)+dz*dz),
// no FMA contraction.
// ---------------------------------------------------------------------------
__global__ __launch_bounds__(T, 2) void fps_multi(
    const float* __restrict__ xyz,             // [B,3,N]
    unsigned long long* __restrict__ keyArr,   // [B][NPOINT] zeroed
    unsigned int* __restrict__ cnt,            // [B][NPOINT] zeroed
    int* __restrict__ cent)                    // [B][NPOINT]
{
    const int b    = blockIdx.x / G;
    const int g    = blockIdx.x % G;
    const int tid  = threadIdx.x;
    const int wave = tid >> 6;
    const int lane = tid & 63;

    const float* X = xyz + (size_t)b * 3 * N_PTS;
    const float* Y = X + N_PTS;
    const float* Z = X + 2 * N_PTS;
    const int base = g * CHUNK;

    float px[KPT], py[KPT], pz[KPT], dst[KPT];
#pragma unroll
    for (int k = 0; k < KPT; ++k) {
        const int p = base + k * T + tid;   // coalesced; ascending per thread
        px[k]  = X[p];
        py[k]  = Y[p];
        pz[k]  = Z[p];
        dst[k] = BIGF;
    }

    __shared__ unsigned long long s_key[2][NWAVE];
    unsigned long long* krow = keyArr + (size_t)b * NPOINT;
    unsigned int*       crow = cnt    + (size_t)b * NPOINT;

    auto sync_reduce = [&](unsigned long long key, int r) -> int {
        // wave butterfly (u64 max)
#pragma unroll
        for (int off = 32; off > 0; off >>= 1) {
            const unsigned long long o = __shfl_xor(key, off);
            if (o > key) key = o;
        }
        const int buf = r & 1;                 // double-buffer: no 2nd barrier
        if (lane == 0) s_key[buf][wave] = key;
        __syncthreads();
        unsigned long long bk = s_key[buf][0];
#pragma unroll
        for (int w = 1; w < NWAVE; ++w) {
            const unsigned long long o = s_key[buf][w];
            if (o > bk) bk = o;
        }
        if (tid == 0) {
            __hip_atomic_fetch_max(&krow[r], bk, __ATOMIC_RELAXED,
                                   __HIP_MEMORY_SCOPE_AGENT);
            __hip_atomic_fetch_add(&crow[r], 1u, __ATOMIC_RELEASE,
                                   __HIP_MEMORY_SCOPE_AGENT);
        }
        unsigned int c;
        do {
            c = __hip_atomic_load(&crow[r], __ATOMIC_ACQUIRE,
                                  __HIP_MEMORY_SCOPE_AGENT);
        } while (c < (unsigned)G);
        const unsigned long long gk =
            __hip_atomic_load(&krow[r], __ATOMIC_RELAXED,
                              __HIP_MEMORY_SCOPE_AGENT);
        return __builtin_amdgcn_readfirstlane(key_idx(gk));
    };

    // ---- initial far: argmax over x (first max) ----
    float bv = px[0];
    int   bi = base + tid;
#pragma unroll
    for (int k = 1; k < KPT; ++k) {
        if (px[k] > bv) { bv = px[k]; bi = base + k * T + tid; }
    }
    int far = sync_reduce(pack_key(bv, bi), 0);

    // ---- main FPS loop ----
    for (int it = 0; it < NPOINT; ++it) {
        if (g == 0 && tid == 0) cent[(size_t)b * NPOINT + it] = far;
        if (it == NPOINT - 1) break;          // last update is unused

        const float cx = X[far];              // far in SGPR -> scalar loads
        const float cy = Y[far];
        const float cz = Z[far];

        float nbv = -1.0f;
        int   nbi = 0;
#pragma unroll
        for (int k = 0; k < KPT; ++k) {
            const float dx = __fsub_rn(px[k], cx);
            const float dy = __fsub_rn(py[k], cy);
            const float dz = __fsub_rn(pz[k], cz);
            const float d  = __fadd_rn(
                __fadd_rn(__fmul_rn(dx, dx), __fmul_rn(dy, dy)),
                __fmul_rn(dz, dz));
            const float nd = fminf(dst[k], d);
            dst[k] = nd;
            if (nd > nbv) { nbv = nd; nbi = base + k * T + tid; }
        }
        far = sync_reduce(pack_key(nbv, nbi), it + 1);
    }
}

// ---------------------------------------------------------------------------
// Fallback single-block FPS (round-2 kernel) if ws_size is too small for the
// multi-block sync arrays.
// ---------------------------------------------------------------------------
__global__ __launch_bounds__(512, 2) void fps_single(
    const float* __restrict__ xyz,
    int* __restrict__ cent)
{
    constexpr int BL = 512, KP = N_PTS / BL, NW = BL / 64;
    const int b   = blockIdx.x;
    const int tid = threadIdx.x;
    const float* X = xyz + (size_t)b * 3 * N_PTS;
    const float* Y = X + N_PTS;
    const float* Z = X + 2 * N_PTS;

    float px[KP], py[KP], pz[KP], dst[KP];
#pragma unroll
    for (int k = 0; k < KP; ++k) {
        const int p = tid + k * BL;
        px[k] = X[p]; py[k] = Y[p]; pz[k] = Z[p]; dst[k] = BIGF;
    }
    __shared__ unsigned long long s_key[2][NW];
    const int wave = tid >> 6, lane = tid & 63;

    float bv = px[0]; int bi = tid;
#pragma unroll
    for (int k = 1; k < KP; ++k)
        if (px[k] > bv) { bv = px[k]; bi = tid + k * BL; }
    unsigned long long key = pack_key(bv, bi);
#pragma unroll
    for (int off = 32; off > 0; off >>= 1) {
        const unsigned long long o = __shfl_xor(key, off);
        if (o > key) key = o;
    }
    if (lane == 0) s_key[0][wave] = key;
    __syncthreads();
    unsigned long long bk = s_key[0][0];
#pragma unroll
    for (int w = 1; w < NW; ++w)
        if (s_key[0][w] > bk) bk = s_key[0][w];
    int far = __builtin_amdgcn_readfirstlane(key_idx(bk));

    for (int it = 0; it < NPOINT; ++it) {
        if (tid == 0) cent[b * NPOINT + it] = far;
        if (it == NPOINT - 1) break;
        const float cx = X[far], cy = Y[far], cz = Z[far];
        float nbv = -1.0f; int nbi = 0;
#pragma unroll
        for (int k = 0; k < KP; ++k) {
            const float dx = __fsub_rn(px[k], cx);
            const float dy = __fsub_rn(py[k], cy);
            const float dz = __fsub_rn(pz[k], cz);
            const float d  = __fadd_rn(
                __fadd_rn(__fmul_rn(dx, dx), __fmul_rn(dy, dy)),
                __fmul_rn(dz, dz));
            const float nd = fminf(dst[k], d);
            dst[k] = nd;
            if (nd > nbv) { nbv = nd; nbi = tid + k * BL; }
        }
        unsigned long long k2 = pack_key(nbv, nbi);
#pragma unroll
        for (int off = 32; off > 0; off >>= 1) {
            const unsigned long long o = __shfl_xor(k2, off);
            if (o > k2) k2 = o;
        }
        const int buf = (it + 1) & 1;
        if (lane == 0) s_key[buf][wave] = k2;
        __syncthreads();
        unsigned long long b2 = s_key[buf][0];
#pragma unroll
        for (int w = 1; w < NW; ++w)
            if (s_key[buf][w] > b2) b2 = s_key[buf][w];
        far = __builtin_amdgcn_readfirstlane(key_idx(b2));
    }
}

// ---------------------------------------------------------------------------
// Ball query, nsample=1: one wave per centroid; scan 64-pt chunks from index
// 0, first hit wins. Distance = reference einsum ((-2*dot)+|c|^2)+|p|^2,
// keep-test d <= 0.25 (== !(d > r^2)).
// ---------------------------------------------------------------------------
__global__ __launch_bounds__(256) void ballq_kernel(
    const float* __restrict__ xyz,
    const int* __restrict__ cent,
    int* __restrict__ out)
{
    const int gw   = (blockIdx.x * 256 + threadIdx.x) >> 6;
    const int lane = threadIdx.x & 63;
    const int b = gw / NPOINT;
    const int s = gw % NPOINT;

    const float* X = xyz + (size_t)b * 3 * N_PTS;
    const float* Y = X + N_PTS;
    const float* Z = X + 2 * N_PTS;

    const int ci = cent[b * NPOINT + s];
    const float cx = X[ci], cy = Y[ci], cz = Z[ci];
    const float cn = __fadd_rn(
        __fadd_rn(__fmul_rn(cx, cx), __fmul_rn(cy, cy)), __fmul_rn(cz, cz));

    int res = N_PTS;
    for (int base = 0; base < N_PTS; base += 64) {
        const int p = base + lane;
        const float x = X[p], y = Y[p], z = Z[p];
        const float dot = __fadd_rn(
            __fadd_rn(__fmul_rn(x, cx), __fmul_rn(y, cy)), __fmul_rn(z, cz));
        const float pn = __fadd_rn(
            __fadd_rn(__fmul_rn(x, x), __fmul_rn(y, y)), __fmul_rn(z, z));
        const float d = __fadd_rn(__fadd_rn(__fmul_rn(-2.0f, dot), cn), pn);
        const unsigned long long m = __ballot(!(d > 0.25f));
        if (m) {
            res = base + (__ffsll((long long)m) - 1);
            break;
        }
    }
    if (lane == 0) out[b * NPOINT + s] = res;
}

extern "C" void kernel_launch(void* const* d_in, const int* in_sizes, int n_in,
                              void* d_out, int out_size, void* d_ws, size_t ws_size,
                              hipStream_t stream) {
    const float* xyz = (const float*)d_in[0];
    const int B = in_sizes[1] / 16;            // cls_label is [B,16]
    int* out = (int*)d_out;

    const size_t keyBytes  = (size_t)B * NPOINT * sizeof(unsigned long long);
    const size_t cntBytes  = (size_t)B * NPOINT * sizeof(unsigned int);
    const size_t centBytes = (size_t)B * NPOINT * sizeof(int);

    if (ws_size >= keyBytes + cntBytes + centBytes) {
        unsigned long long* keyArr = (unsigned long long*)d_ws;
        unsigned int* cnt  = (unsigned int*)((char*)d_ws + keyBytes);
        int*          cent = (int*)((char*)d_ws + keyBytes + cntBytes);
        hipMemsetAsync(d_ws, 0, keyBytes + cntBytes, stream);  // keys + counters
        fps_multi<<<B * G, T, 0, stream>>>(xyz, keyArr, cnt, cent);
        ballq_kernel<<<B * NPOINT / 4, 256, 0, stream>>>(xyz, cent, out);
    } else {
        int* cent = (int*)d_ws;
        fps_single<<<B, 512, 0, stream>>>(xyz, cent);
        ballq_kernel<<<B * NPOINT / 4, 256, 0, stream>>>(xyz, cent, out);
    }
}

// Round 4
// 2140.207 us; speedup vs baseline: 3.4887x; 3.4887x over previous
//
#include <hip/hip_runtime.h>

// PointNet++ front-end on MI355X: FPS (B=4, N=16384, NPOINT=1024) + ball query
// nsample=1, radius=0.5. xyz layout [B,3,N]. Output int32 [B,NPOINT,1].
//
// Round-4 design (single block per batch — round 3 proved per-iter grid sync
// through LLC costs ~7 us/iter, 10x a block barrier):
//  * 1024 threads, 16 pts/thread CONTIGUOUS (lane order == index order).
//  * float2 packed math under fp-contract(off): v_pk_add/mul_f32, exact
//    numpy rounding (((dx*dx+dy*dy)+dz*dz), separate rn, no fma).
//  * wave argmax: 6-step DPP v_max_f32 + ballot equality (first-occurrence
//    tie-break == np.argmax because layout is contiguous).
//  * cross-wave: 16 {val,idx} pairs in LDS, double-buffered, ONE barrier.

constexpr int   N_PTS  = 16384;
constexpr int   NPOINT = 1024;
constexpr int   BLOCK  = 1024;
constexpr int   KPT    = N_PTS / BLOCK;  // 16 points/thread
constexpr int   NPAIR  = KPT / 2;        // 8 float2 per coord array
constexpr int   NWAVE  = BLOCK / 64;     // 16 waves
constexpr float BIGF   = 1e10f;

typedef float v2f __attribute__((ext_vector_type(2)));

// Wave-wide f32 max via DPP (values are all >= 0 here; no NaN/-0 concerns).
// Canonical GCN sequence; result accumulates into lane 63, readlane broadcasts.
__device__ inline float wave_max_f32(float v) {
    int x = __float_as_int(v);
    int t;
    t = __builtin_amdgcn_update_dpp(x, x, 0x111, 0xf, 0xf, false);  // row_shr:1
    x = __float_as_int(fmaxf(__int_as_float(x), __int_as_float(t)));
    t = __builtin_amdgcn_update_dpp(x, x, 0x112, 0xf, 0xf, false);  // row_shr:2
    x = __float_as_int(fmaxf(__int_as_float(x), __int_as_float(t)));
    t = __builtin_amdgcn_update_dpp(x, x, 0x114, 0xf, 0xf, false);  // row_shr:4
    x = __float_as_int(fmaxf(__int_as_float(x), __int_as_float(t)));
    t = __builtin_amdgcn_update_dpp(x, x, 0x118, 0xf, 0xf, false);  // row_shr:8
    x = __float_as_int(fmaxf(__int_as_float(x), __int_as_float(t)));
    t = __builtin_amdgcn_update_dpp(x, x, 0x142, 0xa, 0xf, false);  // bcast15
    x = __float_as_int(fmaxf(__int_as_float(x), __int_as_float(t)));
    t = __builtin_amdgcn_update_dpp(x, x, 0x143, 0xc, 0xf, false);  // bcast31
    x = __float_as_int(fmaxf(__int_as_float(x), __int_as_float(t)));
    return __int_as_float(__builtin_amdgcn_readlane(x, 63));
}

__global__ __launch_bounds__(BLOCK) void fps_kernel(
    const float* __restrict__ xyz,   // [B,3,N]
    int* __restrict__ cent)          // [B,NPOINT]
{
#pragma clang fp contract(off)
    const int b    = blockIdx.x;
    const int tid  = threadIdx.x;
    const int wave = tid >> 6;
    const int lane = tid & 63;
    const int pb   = tid * KPT;      // contiguous ownership: [pb, pb+16)

    const float* X = xyz + (size_t)b * 3 * N_PTS;
    const float* Y = X + N_PTS;
    const float* Z = X + 2 * N_PTS;

    v2f px[NPAIR], py[NPAIR], pz[NPAIR], dst[NPAIR];
#pragma unroll
    for (int j = 0; j < NPAIR; ++j) {
        px[j]  = *(const v2f*)(X + pb + 2 * j);
        py[j]  = *(const v2f*)(Y + pb + 2 * j);
        pz[j]  = *(const v2f*)(Z + pb + 2 * j);
        dst[j] = (v2f){BIGF, BIGF};
    }

    __shared__ uint2 s_red[2][NWAVE];   // {f32 bits of max, winning idx}

    // block argmax with np.argmax first-occurrence tie-break (valid because
    // lane order == index order == wave order under contiguous ownership).
    auto block_argmax = [&](float val, int idx, int r) -> int {
        const float mv = wave_max_f32(val);
        const unsigned long long cand = __ballot(val == mv);
        const int fl   = __ffsll((long long)cand) - 1;   // lowest lane == lowest idx
        const int widx = __builtin_amdgcn_readlane(idx, fl);
        const int buf  = r & 1;                          // double buffer: 1 barrier
        if (lane == 0) {
            s_red[buf][wave] = make_uint2(__float_as_uint(mv), (unsigned)widx);
        }
        __syncthreads();
        uint2 e0 = s_red[buf][0];
        float bv = __uint_as_float(e0.x);
        int   bi = (int)e0.y;
#pragma unroll
        for (int w = 1; w < NWAVE; ++w) {
            const uint2 e = s_red[buf][w];
            const float v = __uint_as_float(e.x);
            if (v > bv) { bv = v; bi = (int)e.y; }       // '>' keeps first wave
        }
        return __builtin_amdgcn_readfirstlane(bi);
    };

    // ---- initial far: argmax over x (first max) ----
    float bv = -1.0f;
    int   bi = 0;
#pragma unroll
    for (int j = 0; j < NPAIR; ++j) {
        if (px[j].x > bv) { bv = px[j].x; bi = pb + 2 * j; }
        if (px[j].y > bv) { bv = px[j].y; bi = pb + 2 * j + 1; }
    }
    int far = block_argmax(bv, bi, 0);

    // ---- main FPS loop ----
    for (int it = 0; it < NPOINT; ++it) {
        if (tid == 0) cent[b * NPOINT + it] = far;   // record PRE-update far
        if (it == NPOINT - 1) break;                 // last update unused

        const float cx = X[far];                     // uniform -> scalar loads
        const float cy = Y[far];
        const float cz = Z[far];
        const v2f c2x = {cx, cx}, c2y = {cy, cy}, c2z = {cz, cz};

        float nbv = -1.0f;
        int   nbi = 0;
#pragma unroll
        for (int j = 0; j < NPAIR; ++j) {
            const v2f dx = px[j] - c2x;              // v_pk_add_f32 (neg)
            const v2f dy = py[j] - c2y;
            const v2f dz = pz[j] - c2z;
            const v2f d  = (dx * dx + dy * dy) + dz * dz;  // pk_mul/pk_add, rn
            v2f nd;
            nd.x = fminf(dst[j].x, d.x);
            nd.y = fminf(dst[j].y, d.y);
            dst[j] = nd;
            if (nd.x > nbv) { nbv = nd.x; nbi = pb + 2 * j; }
            if (nd.y > nbv) { nbv = nd.y; nbi = pb + 2 * j + 1; }
        }
        far = block_argmax(nbv, nbi, it + 1);
    }
}

// ---------------------------------------------------------------------------
// Ball query, nsample=1: one wave per centroid; scan 64-pt chunks from index
// 0, first hit wins (== min index within radius). Distance = reference einsum
// ((-2*dot)+|c|^2)+|p|^2; keep-test d <= 0.25 (== !(d > r^2)).
// ---------------------------------------------------------------------------
__global__ __launch_bounds__(256) void ballq_kernel(
    const float* __restrict__ xyz,
    const int* __restrict__ cent,
    int* __restrict__ out)
{
    const int gw   = (blockIdx.x * 256 + threadIdx.x) >> 6;
    const int lane = threadIdx.x & 63;
    const int b = gw / NPOINT;
    const int s = gw % NPOINT;

    const float* X = xyz + (size_t)b * 3 * N_PTS;
    const float* Y = X + N_PTS;
    const float* Z = X + 2 * N_PTS;

    const int ci = cent[b * NPOINT + s];
    const float cx = X[ci], cy = Y[ci], cz = Z[ci];
    const float cn = __fadd_rn(
        __fadd_rn(__fmul_rn(cx, cx), __fmul_rn(cy, cy)), __fmul_rn(cz, cz));

    int res = N_PTS;
    for (int base = 0; base < N_PTS; base += 64) {
        const int p = base + lane;
        const float x = X[p], y = Y[p], z = Z[p];
        const float dot = __fadd_rn(
            __fadd_rn(__fmul_rn(x, cx), __fmul_rn(y, cy)), __fmul_rn(z, cz));
        const float pn = __fadd_rn(
            __fadd_rn(__fmul_rn(x, x), __fmul_rn(y, y)), __fmul_rn(z, z));
        const float d = __fadd_rn(__fadd_rn(__fmul_rn(-2.0f, dot), cn), pn);
        const unsigned long long m = __ballot(!(d > 0.25f));
        if (m) {
            res = base + (__ffsll((long long)m) - 1);
            break;
        }
    }
    if (lane == 0) out[b * NPOINT + s] = res;
}

extern "C" void kernel_launch(void* const* d_in, const int* in_sizes, int n_in,
                              void* d_out, int out_size, void* d_ws, size_t ws_size,
                              hipStream_t stream) {
    const float* xyz = (const float*)d_in[0];
    const int B = in_sizes[1] / 16;            // cls_label is [B,16]
    int* out = (int*)d_out;

    // cent scratch: d_ws if it fits, else alias d_out (safe: ballq wave (b,s)
    // reads cent[b,s] before writing out[b,s], element-wise aliasing only).
    int* cent = (ws_size >= (size_t)B * NPOINT * sizeof(int)) ? (int*)d_ws
                                                              : (int*)d_out;

    fps_kernel<<<B, BLOCK, 0, stream>>>(xyz, cent);
    ballq_kernel<<<B * NPOINT / 4, 256, 0, stream>>>(xyz, cent, out);
}

// Round 5
// 1955.182 us; speedup vs baseline: 3.8188x; 1.0946x over previous
//
#include <hip/hip_runtime.h>

// PointNet++ front-end on MI355X: FPS (B=4, N=16384, NPOINT=1024) + ball query
// nsample=1, radius=0.5. xyz layout [B,3,N]. Output int32 [B,NPOINT,1].
//
// Round-5 design (single block per batch; R3 proved grid sync is ~10x worse):
//  * 512 threads, 32 pts/thread CONTIGUOUS; px/py/pz/dst in VGPRs, PINNED via
//    empty inline-asm "+v" each iteration (R1/R2/R4 showed the compiler
//    demotes them to AGPR/reload otherwise: VGPR_Count < array size).
//  * amdgpu_waves_per_eu(2,2): exactly 2 waves/SIMD -> 256-reg budget, no
//    occupancy incentive to shrink (only 4 blocks run on 256 CUs).
//  * scan is value-only (pk add/mul + v_min + v_max3); argmax index resolved
//    once per wave via DPP max + ballot + single-lane rescan. First-occurrence
//    tie-break (np.argmax) preserved: wave order == lane order == index order.
//  * numerics bit-match numpy: fp contract off, ((dx*dx+dy*dy)+dz*dz), each
//    op round-to-nearest; fmin/fmax on non-NaN values.

constexpr int   N_PTS  = 16384;
constexpr int   NPOINT = 1024;
constexpr int   BLOCK  = 512;
constexpr int   KPT    = N_PTS / BLOCK;   // 32 points/thread
constexpr int   NPAIR  = KPT / 2;         // 16 float2 per coord
constexpr int   NWAVE  = BLOCK / 64;      // 8 waves
constexpr float BIGF   = 1e10f;

typedef float v2f __attribute__((ext_vector_type(2)));

// Wave-wide f32 max via DPP (values >= 0, no NaN). Verified in round 4.
__device__ inline float wave_max_f32(float v) {
    int x = __float_as_int(v);
    int t;
    t = __builtin_amdgcn_update_dpp(x, x, 0x111, 0xf, 0xf, false);  // row_shr:1
    x = __float_as_int(fmaxf(__int_as_float(x), __int_as_float(t)));
    t = __builtin_amdgcn_update_dpp(x, x, 0x112, 0xf, 0xf, false);  // row_shr:2
    x = __float_as_int(fmaxf(__int_as_float(x), __int_as_float(t)));
    t = __builtin_amdgcn_update_dpp(x, x, 0x114, 0xf, 0xf, false);  // row_shr:4
    x = __float_as_int(fmaxf(__int_as_float(x), __int_as_float(t)));
    t = __builtin_amdgcn_update_dpp(x, x, 0x118, 0xf, 0xf, false);  // row_shr:8
    x = __float_as_int(fmaxf(__int_as_float(x), __int_as_float(t)));
    t = __builtin_amdgcn_update_dpp(x, x, 0x142, 0xa, 0xf, false);  // bcast15
    x = __float_as_int(fmaxf(__int_as_float(x), __int_as_float(t)));
    t = __builtin_amdgcn_update_dpp(x, x, 0x143, 0xc, 0xf, false);  // bcast31
    x = __float_as_int(fmaxf(__int_as_float(x), __int_as_float(t)));
    return __int_as_float(__builtin_amdgcn_readlane(x, 63));
}

__global__ __launch_bounds__(BLOCK)
__attribute__((amdgpu_waves_per_eu(2, 2)))
void fps_kernel(const float* __restrict__ xyz,   // [B,3,N]
                int* __restrict__ cent)          // [B,NPOINT]
{
#pragma clang fp contract(off)
    const int b    = blockIdx.x;
    const int tid  = threadIdx.x;
    const int wave = tid >> 6;
    const int lane = tid & 63;
    const int pb   = tid * KPT;      // contiguous ownership: [pb, pb+32)

    const float* X = xyz + (size_t)b * 3 * N_PTS;
    const float* Y = X + N_PTS;
    const float* Z = X + 2 * N_PTS;

    v2f px[NPAIR], py[NPAIR], pz[NPAIR], dst[NPAIR];
#pragma unroll
    for (int j = 0; j < NPAIR; ++j) {
        px[j]  = *(const v2f*)(X + pb + 2 * j);
        py[j]  = *(const v2f*)(Y + pb + 2 * j);
        pz[j]  = *(const v2f*)(Z + pb + 2 * j);
        dst[j] = (v2f){BIGF, BIGF};
    }

    __shared__ uint2 s_red[2][NWAVE];   // {f32 bits of wave max, wave argmax}

    // Cross-wave combine (ONE barrier, double-buffered). '>' keeps the first
    // (lowest-index) wave on ties == np.argmax semantics.
    auto cross_wave = [&](float mv, int widx, int r) -> int {
        const int buf = r & 1;
        if (lane == 0)
            s_red[buf][wave] = make_uint2(__float_as_uint(mv), (unsigned)widx);
        __syncthreads();
        uint2 e0 = s_red[buf][0];
        float bv = __uint_as_float(e0.x);
        int   bi = (int)e0.y;
#pragma unroll
        for (int w = 1; w < NWAVE; ++w) {
            const uint2 e = s_red[buf][w];
            const float v = __uint_as_float(e.x);
            if (v > bv) { bv = v; bi = (int)e.y; }
        }
        return __builtin_amdgcn_readfirstlane(bi);
    };

    // ---- initial far: argmax over x (first occurrence) ----
    int far;
    {
        float m = -1.0f;
#pragma unroll
        for (int j = 0; j < NPAIR; ++j)
            m = fmaxf(m, fmaxf(px[j].x, px[j].y));     // -> v_max3_f32
        const float mv = wave_max_f32(m);
        const unsigned long long match = __ballot(m == mv);
        const int fl = __ffsll((long long)match) - 1;  // lowest lane == lowest idx
        int idx = 0;
        if (lane == fl) {
            // descending overwrite => first (ascending) match wins
#pragma unroll
            for (int j = NPAIR - 1; j >= 0; --j) {
                if (px[j].y == mv) idx = pb + 2 * j + 1;
                if (px[j].x == mv) idx = pb + 2 * j;
            }
        }
        idx = __builtin_amdgcn_readlane(idx, fl);
        far = cross_wave(mv, idx, 0);
    }

    // ---- main FPS loop ----
    for (int it = 0; it < NPOINT; ++it) {
        if (tid == 0) cent[b * NPOINT + it] = far;   // record PRE-update far
        if (it == NPOINT - 1) break;                 // last update unused

        // Pin point arrays in arch VGPRs (zero-inst barrier: stops the
        // compiler demoting them to AGPRs / reloading from memory).
#pragma unroll
        for (int j = 0; j < NPAIR; ++j)
            asm volatile("" : "+v"(px[j]), "+v"(py[j]), "+v"(pz[j]));

        const float cx = X[far];                     // uniform -> scalar loads
        const float cy = Y[far];
        const float cz = Z[far];
        const v2f c2x = {cx, cx}, c2y = {cy, cy}, c2z = {cz, cz};

        float m = -1.0f;
#pragma unroll
        for (int j = 0; j < NPAIR; ++j) {
            const v2f dx = px[j] - c2x;              // v_pk_add_f32 (neg mod)
            const v2f dy = py[j] - c2y;
            const v2f dz = pz[j] - c2z;
            const v2f d  = (dx * dx + dy * dy) + dz * dz;  // pk ops, each rn
            dst[j].x = fminf(dst[j].x, d.x);
            dst[j].y = fminf(dst[j].y, d.y);
            m = fmaxf(m, fmaxf(dst[j].x, dst[j].y)); // -> v_max3_f32
        }

        const float mv = wave_max_f32(m);
        const unsigned long long match = __ballot(m == mv);
        const int fl = __ffsll((long long)match) - 1;
        int idx = 0;
        if (lane == fl) {
#pragma unroll
            for (int j = NPAIR - 1; j >= 0; --j) {
                if (dst[j].y == mv) idx = pb + 2 * j + 1;
                if (dst[j].x == mv) idx = pb + 2 * j;
            }
        }
        idx = __builtin_amdgcn_readlane(idx, fl);
        far = cross_wave(mv, idx, it + 1);
    }
}

// ---------------------------------------------------------------------------
// Ball query, nsample=1: one wave per centroid; scan 64-pt chunks from index
// 0, first hit wins (== min index within radius). Distance = reference einsum
// ((-2*dot)+|c|^2)+|p|^2; keep-test d <= 0.25 (== !(d > r^2)).
// ---------------------------------------------------------------------------
__global__ __launch_bounds__(256) void ballq_kernel(
    const float* __restrict__ xyz,
    const int* __restrict__ cent,
    int* __restrict__ out)
{
    const int gw   = (blockIdx.x * 256 + threadIdx.x) >> 6;
    const int lane = threadIdx.x & 63;
    const int b = gw / NPOINT;
    const int s = gw % NPOINT;

    const float* X = xyz + (size_t)b * 3 * N_PTS;
    const float* Y = X + N_PTS;
    const float* Z = X + 2 * N_PTS;

    const int ci = cent[b * NPOINT + s];
    const float cx = X[ci], cy = Y[ci], cz = Z[ci];
    const float cn = __fadd_rn(
        __fadd_rn(__fmul_rn(cx, cx), __fmul_rn(cy, cy)), __fmul_rn(cz, cz));

    int res = N_PTS;
    for (int base = 0; base < N_PTS; base += 64) {
        const int p = base + lane;
        const float x = X[p], y = Y[p], z = Z[p];
        const float dot = __fadd_rn(
            __fadd_rn(__fmul_rn(x, cx), __fmul_rn(y, cy)), __fmul_rn(z, cz));
        const float pn = __fadd_rn(
            __fadd_rn(__fmul_rn(x, x), __fmul_rn(y, y)), __fmul_rn(z, z));
        const float d = __fadd_rn(__fadd_rn(__fmul_rn(-2.0f, dot), cn), pn);
        const unsigned long long m = __ballot(!(d > 0.25f));
        if (m) {
            res = base + (__ffsll((long long)m) - 1);
            break;
        }
    }
    if (lane == 0) out[b * NPOINT + s] = res;
}

extern "C" void kernel_launch(void* const* d_in, const int* in_sizes, int n_in,
                              void* d_out, int out_size, void* d_ws, size_t ws_size,
                              hipStream_t stream) {
    const float* xyz = (const float*)d_in[0];
    const int B = in_sizes[1] / 16;            // cls_label is [B,16]
    int* out = (int*)d_out;

    // cent scratch: d_ws if it fits, else alias d_out (safe: ballq wave (b,s)
    // reads cent[b,s] before writing out[b,s], element-wise aliasing only).
    int* cent = (ws_size >= (size_t)B * NPOINT * sizeof(int)) ? (int*)d_ws
                                                              : (int*)d_out;

    fps_kernel<<<B, BLOCK, 0, stream>>>(xyz, cent);
    ballq_kernel<<<B * NPOINT / 4, 256, 0, stream>>>(xyz, cent, out);
}